// Round 3
// baseline (868.566 us; speedup 1.0000x reference)
//
#include <hip/hip_runtime.h>
#include <hip/hip_bf16.h>

#define Hh 256
#define Ii 128
#define Bb 512
#define KF 384   // 128 (x) + 256 (hx) feature dim
#define KB 64    // k-block width per block
#define LDB 40   // padded LDS stride for sB (bf16 elems)

typedef __attribute__((ext_vector_type(8))) short bf16x8;
typedef __attribute__((ext_vector_type(4))) float f32x4;
typedef unsigned short u16;
typedef unsigned int u32;

__device__ inline float bf2f(u16 u) { return __uint_as_float(((u32)u) << 16); }
__device__ inline u16 f2bf(float f) {
  u32 u = __float_as_uint(f);
  u += 0x7FFFu + ((u >> 16) & 1u);   // RNE
  return (u16)(u >> 16);
}
__device__ inline u32 pack_bf16x2(float a, float b) {
  __hip_bfloat162 h = __float22bfloat162_rn(make_float2(a, b));  // v_cvt_pk_bf16_f32
  u32 r; __builtin_memcpy(&r, &h, 4); return r;
}
__device__ inline float sigm(float x) { return 1.0f / (1.0f + __expf(-x)); }
__device__ inline float tanh_f(float x) { return 1.0f - 2.0f / (1.0f + __expf(2.0f * x)); }

// sP swizzle: (j',kk) -> j'*64 + ((kk>>3 ^ (j'&7))<<3 | (kk&7)); 8-elem chunks
// stay contiguous (b128-able) while XOR spreads banks. 16 KB for 128x64.
__device__ inline int sp_idx(int j, int kk) {
  return j * 64 + ((((kk >> 3) ^ (j & 7)) << 3) | (kk & 7));
}

// ---------------- kernel 0: pack weights/bias, transpose Vtinv, zero proj ----
__global__ __launch_bounds__(256) void k_prep(
    const float* __restrict__ Wii, const float* __restrict__ Wif, const float* __restrict__ Wig,
    const float* __restrict__ Whi, const float* __restrict__ Whit,
    const float* __restrict__ Whf, const float* __restrict__ Whft,
    const float* __restrict__ Whc, const float* __restrict__ Whct,
    const float* __restrict__ Vtinv,
    const float* __restrict__ bi, const float* __restrict__ bfm, const float* __restrict__ bg,
    u16* __restrict__ RW, u16* __restrict__ CW, u16* __restrict__ Vtt,
    u16* __restrict__ biasP, float* __restrict__ proj) {
  const int tid = threadIdx.x, bx = blockIdx.x, y = blockIdx.y;
  if (y < 3) {
    const float* WX  = (y == 0) ? Wii : (y == 1 ? Wif : Wig);
    const float* WHr = (y == 0) ? Whi : (y == 1 ? Whf : Whc);
    const float* WHt = (y == 0) ? Whit : (y == 1 ? Whft : Whct);
    u16* rw = RW + y * Hh * KF;
    u16* cw = CW + y * Hh * KF;
#pragma unroll
    for (int it = 0; it < 4; ++it) {
      int idx = it * 24576 + bx * 256 + tid;   // 0..98303
      int h = idx / KF, t = idx - h * KF;
      float a, c;
      if (t < Ii) { a = WX[h * Ii + t]; c = a; }
      else        { a = WHr[h * Hh + t - Ii]; c = WHt[h * Hh + t - Ii]; }
      rw[idx] = f2bf(a);
      cw[idx] = f2bf(c);
    }
  } else if (y == 3) {
    if (bx < 64) {
      // Vtt[i][k] = Vtinv[k][i], 32x32 LDS tile transpose
      __shared__ u16 tbuf[32][33];
      const int c = tid & 31, r8 = tid >> 5;
      const int tr = bx >> 3, tc = bx & 7;
#pragma unroll
      for (int rr = r8; rr < 32; rr += 8)
        tbuf[rr][c] = f2bf(Vtinv[(tc * 32 + rr) * Hh + tr * 32 + c]);
      __syncthreads();
#pragma unroll
      for (int rr = r8; rr < 32; rr += 8)
        Vtt[(tr * 32 + rr) * Hh + tc * 32 + c] = tbuf[c][rr];
    } else if (bx < 96) {
      // zero proj: 32 blocks x 256 threads x 4 x float4 = 131072 floats
      const int base = (bx - 64) * 256 + tid;
      const float4 z = {0.f, 0.f, 0.f, 0.f};
#pragma unroll
      for (int it = 0; it < 4; ++it)
        *(float4*)(proj + (size_t)(it * 8192 + base) * 4) = z;
    }
  } else {
    // biasP: phase-ordered (0=bg,1=bi,2=bf), laid out thread-contiguous in the
    // MFMA C fragment order so k_main loads 32 bf16 as 4 coalesced uint4.
    const int base = (bx * 256 + tid) * 8;
#pragma unroll
    for (int e8 = 0; e8 < 8; ++e8) {
      int f = base + e8;                    // 0..196607
      int g = f >> 16;
      int r1 = f & 65535;
      int jb = r1 >> 15;
      int r2 = r1 & 32767;
      int kb = r2 >> 13;
      int r3 = r2 & 8191;
      int t  = r3 >> 5;
      int e  = r3 & 31;
      int w = t >> 6, quad = (t >> 4) & 3, r15 = t & 15;
      int ti = e >> 4, tk = (e >> 2) & 3, rr = e & 3;
      int j   = jb * 128 + w * 32 + ti * 16 + quad * 4 + rr;
      int col = kb * 64 + tk * 16 + r15;
      const float* src = (g == 0) ? bg : (g == 1 ? bi : bfm);
      biasP[f] = f2bf(src[j * Hh + col]);
    }
  }
}

// ---------------- kernel 1: fused gates + cell + down-projection -------------
// grid 4096 = b(512) x jb(2) x kb(4); 256 threads = 4 waves.
// Gates: z[j,kk] tile 128(j) x 64(kk), K=384 in 12 chunks; B (CW rows, scaled
// by v_b) staged in LDS dbuf; A (RW rows) raw from global/L2. p,c accumulate
// in REGISTERS (thread-local across gates); c -> LDS once for projection.
__global__ __launch_bounds__(256, 4) void k_main(
    const float* __restrict__ x, const float* __restrict__ hx, const float* __restrict__ cx,
    const float* __restrict__ Uinv, const u16* __restrict__ RW, const u16* __restrict__ CW,
    const u16* __restrict__ Vtt, const u16* __restrict__ biasP, float* __restrict__ proj) {
  __shared__ u16 sP[128 * 64];       // 16384 B, swizzled c-tile [j'][kk]
  __shared__ u16 sB[2 * KB * LDB];   // 10240 B, double-buffered scaled-B
  __shared__ float sV[KF];           //  1536 B

  const int tid  = threadIdx.x;
  const int b    = blockIdx.x >> 3;
  const int jb   = (blockIdx.x >> 2) & 1;
  const int kb   = blockIdx.x & 3;
  const int k0   = kb * KB;
  const int lane = tid & 63;
  const int w    = tid >> 6;
  const int r15  = lane & 15;
  const int quad = lane >> 4;
  const int jbase = jb * 128 + w * 32;   // wave's gate-row slab (global j)
  const int brow = tid >> 2, bcg = tid & 3;

  if (tid < Ii) sV[tid] = x[b * Ii + tid];
  sV[Ii + tid] = hx[b * Hh + tid];
  __syncthreads();   // sV ready for all staging

  float p[2][4][4];
  f32x4 acc[2][4];

  for (int phase = 0; phase < 3; ++phase) {
    const int g = (phase == 0) ? 2 : (phase == 1 ? 0 : 1);   // gate order: g,i,f
    const u16* rw = RW + g * Hh * KF;
    const u16* cw = CW + g * Hh * KF;

#pragma unroll
    for (int ti = 0; ti < 2; ++ti)
#pragma unroll
      for (int tk = 0; tk < 4; ++tk)
#pragma unroll
        for (int r = 0; r < 4; ++r) acc[ti][tk][r] = 0.0f;

    // prologue: stage chunk 0 into buf 0; prefetch fa for chunk 0
    bf16x8 fa[2];
#pragma unroll
    for (int ti = 0; ti < 2; ++ti)
      fa[ti] = *(const bf16x8*)(rw + (jbase + ti * 16 + r15) * KF + quad * 8);
    {
      union { uint4 v; u16 u[8]; } in;
      union { uint4 v; u32 d[4]; } ov;
      in.v = *(const uint4*)(cw + (k0 + brow) * KF + bcg * 8);
      const float4 v0 = *(const float4*)(&sV[bcg * 8]);
      const float4 v1 = *(const float4*)(&sV[bcg * 8 + 4]);
      ov.d[0] = pack_bf16x2(bf2f(in.u[0]) * v0.x, bf2f(in.u[1]) * v0.y);
      ov.d[1] = pack_bf16x2(bf2f(in.u[2]) * v0.z, bf2f(in.u[3]) * v0.w);
      ov.d[2] = pack_bf16x2(bf2f(in.u[4]) * v1.x, bf2f(in.u[5]) * v1.y);
      ov.d[3] = pack_bf16x2(bf2f(in.u[6]) * v1.z, bf2f(in.u[7]) * v1.w);
      *(uint4*)(sB + brow * LDB + bcg * 8) = ov.v;
    }
    __syncthreads();

#pragma unroll
    for (int kc = 0; kc < 12; ++kc) {
      const int cur = kc & 1, nxt = cur ^ 1;
      uint4 bnx;
      bf16x8 fan[2];
      if (kc < 11) {
        bnx = *(const uint4*)(cw + (k0 + brow) * KF + (kc + 1) * 32 + bcg * 8);
#pragma unroll
        for (int ti = 0; ti < 2; ++ti)
          fan[ti] = *(const bf16x8*)(rw + (jbase + ti * 16 + r15) * KF + (kc + 1) * 32 + quad * 8);
      }
      bf16x8 fb[4];
#pragma unroll
      for (int tk = 0; tk < 4; ++tk)
        fb[tk] = *(const bf16x8*)(&sB[cur * (KB * LDB) + (tk * 16 + r15) * LDB + quad * 8]);
#pragma unroll
      for (int ti = 0; ti < 2; ++ti)
#pragma unroll
        for (int tk = 0; tk < 4; ++tk)
          acc[ti][tk] = __builtin_amdgcn_mfma_f32_16x16x32_bf16(fa[ti], fb[tk], acc[ti][tk], 0, 0, 0);
      if (kc < 11) {
        union { uint4 v; u16 u[8]; } in;
        union { uint4 v; u32 d[4]; } ov;
        in.v = bnx;
        const float4 v0 = *(const float4*)(&sV[(kc + 1) * 32 + bcg * 8]);
        const float4 v1 = *(const float4*)(&sV[(kc + 1) * 32 + bcg * 8 + 4]);
        ov.d[0] = pack_bf16x2(bf2f(in.u[0]) * v0.x, bf2f(in.u[1]) * v0.y);
        ov.d[1] = pack_bf16x2(bf2f(in.u[2]) * v0.z, bf2f(in.u[3]) * v0.w);
        ov.d[2] = pack_bf16x2(bf2f(in.u[4]) * v1.x, bf2f(in.u[5]) * v1.y);
        ov.d[3] = pack_bf16x2(bf2f(in.u[6]) * v1.z, bf2f(in.u[7]) * v1.w);
        *(uint4*)(sB + nxt * (KB * LDB) + brow * LDB + bcg * 8) = ov.v;
#pragma unroll
        for (int ti = 0; ti < 2; ++ti) fa[ti] = fan[ti];
      }
      __syncthreads();
    }

    // combine (register p/c). C/D layout: col(kk)=lane&15, row(j)=quad*4+reg.
    union { uint4 v[4]; u16 u[32]; } bb;
    {
      const u16* bp = biasP + (((size_t)(phase * 2 + jb) * 4 + kb) * 256 + tid) * 32;
#pragma unroll
      for (int q = 0; q < 4; ++q) bb.v[q] = *(const uint4*)(bp + q * 8);
    }
    if (phase == 2) {
      // c = sigm(zf)*cx + p; write c-tile to LDS (bf16) for the projection
      const float* cx_b = cx + (size_t)b * Hh * Hh;
      float cxv[2][4][4];
#pragma unroll
      for (int ti = 0; ti < 2; ++ti)
#pragma unroll
        for (int tk = 0; tk < 4; ++tk)
#pragma unroll
          for (int r = 0; r < 4; ++r)
            cxv[ti][tk][r] = cx_b[(jbase + ti * 16 + quad * 4 + r) * Hh + k0 + tk * 16 + r15];
#pragma unroll
      for (int ti = 0; ti < 2; ++ti)
#pragma unroll
        for (int tk = 0; tk < 4; ++tk)
#pragma unroll
          for (int r = 0; r < 4; ++r) {
            const int e = ti * 16 + tk * 4 + r;
            float z = acc[ti][tk][r] + bf2f(bb.u[e]);
            float c = sigm(z) * cxv[ti][tk][r] + p[ti][tk][r];
            const int jl = w * 32 + ti * 16 + quad * 4 + r;   // local j in [0,128)
            const int kk = tk * 16 + r15;
            sP[sp_idx(jl, kk)] = f2bf(c);
          }
    } else {
#pragma unroll
      for (int ti = 0; ti < 2; ++ti)
#pragma unroll
        for (int tk = 0; tk < 4; ++tk)
#pragma unroll
          for (int r = 0; r < 4; ++r) {
            const int e = ti * 16 + tk * 4 + r;
            float z = acc[ti][tk][r] + bf2f(bb.u[e]);
            if (phase == 0) p[ti][tk][r] = tanh_f(z);
            else            p[ti][tk][r] *= sigm(z);
          }
    }
  }

  // ---- projection: M[i,j] = sum_{k in block} Vt_t[i,k] * c[j,k], then
  //      racc[i] += M[i,j]*Uinv[i,j] over this block's j-range ----
  bf16x8 va[4][2];
#pragma unroll
  for (int ti = 0; ti < 4; ++ti)
#pragma unroll
    for (int ks = 0; ks < 2; ++ks)
      va[ti][ks] = *(const bf16x8*)(Vtt + (w * 64 + ti * 16 + r15) * Hh + k0 + ks * 32 + quad * 8);
  __syncthreads();   // c-tile complete

  float racc[4][4];
#pragma unroll
  for (int ti = 0; ti < 4; ++ti)
#pragma unroll
    for (int r = 0; r < 4; ++r) racc[ti][r] = 0.0f;

  for (int jt = 0; jt < 2; ++jt) {
    bf16x8 fbp[2][4];
#pragma unroll
    for (int ks = 0; ks < 2; ++ks)
#pragma unroll
      for (int tj = 0; tj < 4; ++tj) {
        const int j = jt * 64 + tj * 16 + r15;
        const int ch = (ks * 4 + quad) ^ (j & 7);
        fbp[ks][tj] = *(const bf16x8*)(&sP[j * 64 + ch * 8]);
      }
#pragma unroll
    for (int ti = 0; ti < 4; ++ti) {
      f32x4 pacc[4];
#pragma unroll
      for (int tj = 0; tj < 4; ++tj)
#pragma unroll
        for (int r = 0; r < 4; ++r) pacc[tj][r] = 0.0f;
#pragma unroll
      for (int ks = 0; ks < 2; ++ks)
#pragma unroll
        for (int tj = 0; tj < 4; ++tj)
          pacc[tj] = __builtin_amdgcn_mfma_f32_16x16x32_bf16(va[ti][ks], fbp[ks][tj], pacc[tj], 0, 0, 0);
#pragma unroll
      for (int tj = 0; tj < 4; ++tj)
#pragma unroll
        for (int r = 0; r < 4; ++r) {
          const int i  = w * 64 + ti * 16 + quad * 4 + r;
          const int jj = jb * 128 + jt * 64 + tj * 16 + r15;
          racc[ti][r] += pacc[tj][r] * Uinv[i * Hh + jj];
        }
    }
  }

#pragma unroll
  for (int ti = 0; ti < 4; ++ti)
#pragma unroll
    for (int r = 0; r < 4; ++r) {
      float v = racc[ti][r];
      v += __shfl_xor(v, 1);
      v += __shfl_xor(v, 2);
      v += __shfl_xor(v, 4);
      v += __shfl_xor(v, 8);
      if (r15 == 0) atomicAdd(&proj[b * Hh + w * 64 + ti * 16 + quad * 4 + r], v);
    }
}

// ---------------- kernel 2: o-gate + final output ---------------------------
__global__ __launch_bounds__(256) void k_out(
    const float* __restrict__ x, const float* __restrict__ hx,
    const float* __restrict__ Wio, const float* __restrict__ Who,
    const float* __restrict__ bo, const float* __restrict__ proj,
    float* __restrict__ out) {
  __shared__ float sv[KF];
  const int b = blockIdx.x, tid = threadIdx.x;
  const int lane = tid & 63, w = tid >> 6;
  if (tid < Ii) sv[tid] = x[b * Ii + tid];
  sv[Ii + tid] = hx[b * Hh + tid];
  __syncthreads();
  for (int rr = 0; rr < 64; ++rr) {
    const int h = w * 64 + rr;
    float p = Wio[h * Ii + lane]        * sv[lane]
            + Wio[h * Ii + 64 + lane]   * sv[64 + lane]
            + Who[h * Hh + lane]        * sv[128 + lane]
            + Who[h * Hh + 64 + lane]   * sv[192 + lane]
            + Who[h * Hh + 128 + lane]  * sv[256 + lane]
            + Who[h * Hh + 192 + lane]  * sv[320 + lane];
    p += __shfl_xor(p, 32);
    p += __shfl_xor(p, 16);
    p += __shfl_xor(p, 8);
    p += __shfl_xor(p, 4);
    p += __shfl_xor(p, 2);
    p += __shfl_xor(p, 1);
    if (lane == 0)
      out[b * Hh + h] = sigm(p + bo[h]) * sigm(proj[b * Hh + h]);
  }
}

extern "C" void kernel_launch(void* const* d_in, const int* in_sizes, int n_in,
                              void* d_out, int out_size, void* d_ws, size_t ws_size,
                              hipStream_t stream) {
  (void)in_sizes; (void)n_in; (void)out_size; (void)ws_size;
  const float* x    = (const float*)d_in[0];
  const float* hx   = (const float*)d_in[1];
  const float* cx   = (const float*)d_in[2];
  const float* Wii  = (const float*)d_in[3];
  const float* Wif  = (const float*)d_in[4];
  const float* Wig  = (const float*)d_in[5];
  const float* Wio  = (const float*)d_in[6];
  const float* Whi  = (const float*)d_in[7];
  const float* Whit = (const float*)d_in[8];
  const float* Whf  = (const float*)d_in[9];
  const float* Whft = (const float*)d_in[10];
  const float* Whc  = (const float*)d_in[11];
  const float* Whct = (const float*)d_in[12];
  const float* Who  = (const float*)d_in[13];
  const float* Uinv = (const float*)d_in[14];
  const float* Vtinv= (const float*)d_in[15];
  const float* bi   = (const float*)d_in[16];
  const float* bf   = (const float*)d_in[17];
  const float* bg   = (const float*)d_in[18];
  const float* bo   = (const float*)d_in[19];
  float* out = (float*)d_out;

  // workspace (~2.23 MB): RW[3], CW[3], Vtt, biasP (bf16); proj (f32)
  u16* RW    = (u16*)d_ws;
  u16* CW    = RW + 3 * Hh * KF;
  u16* Vtt   = CW + 3 * Hh * KF;
  u16* biasP = Vtt + Hh * Hh;
  float* proj = (float*)(biasP + 3 * Hh * Hh);

  k_prep<<<dim3(96, 5), 256, 0, stream>>>(Wii, Wif, Wig, Whi, Whit, Whf, Whft, Whc, Whct,
                                          Vtinv, bi, bf, bg, RW, CW, Vtt, biasP, proj);
  k_main<<<4096, 256, 0, stream>>>(x, hx, cx, Uinv, RW, CW, Vtt, biasP, proj);
  k_out<<<512, 256, 0, stream>>>(x, hx, Wio, Who, bo, proj, out);
}

// Round 4
// 825.779 us; speedup vs baseline: 1.0518x; 1.0518x over previous
//
#include <hip/hip_runtime.h>
#include <hip/hip_bf16.h>

#define Hh 256
#define Ii 128
#define Bb 512
#define KF 384   // 128 (x) + 256 (hx) feature dim
#define KB 64    // k-block width per block

typedef __attribute__((ext_vector_type(8))) short bf16x8;
typedef __attribute__((ext_vector_type(4))) float f32x4;
typedef unsigned short u16;
typedef unsigned int u32;

__device__ inline float bf2f(u16 u) { return __uint_as_float(((u32)u) << 16); }
__device__ inline u16 f2bf(float f) {
  u32 u = __float_as_uint(f);
  u += 0x7FFFu + ((u >> 16) & 1u);   // RNE
  return (u16)(u >> 16);
}
__device__ inline u32 pack_bf16x2(float a, float b) {
  __hip_bfloat162 h = __float22bfloat162_rn(make_float2(a, b));  // v_cvt_pk_bf16_f32
  u32 r; __builtin_memcpy(&r, &h, 4); return r;
}
// scale packed bf16 pair (lo=elem e, hi=elem e+1) by (va, vb), repack to bf16x2
__device__ inline u32 scale2(u32 packed, float va, float vb) {
  float lo = __uint_as_float(packed << 16) * va;
  float hi = __uint_as_float(packed & 0xFFFF0000u) * vb;
  return pack_bf16x2(lo, hi);
}
__device__ inline float sigm(float x) { return 1.0f / (1.0f + __expf(-x)); }
__device__ inline float tanh_f(float x) { return 1.0f - 2.0f / (1.0f + __expf(2.0f * x)); }

// sP swizzle: (j',kk) -> j'*64 + ((kk>>3 ^ (j'&7))<<3 | (kk&7)); 8-elem chunks
// stay contiguous (b128-able) while XOR spreads banks. 16 KB for 128x64.
__device__ inline int sp_idx(int j, int kk) {
  return j * 64 + ((((kk >> 3) ^ (j & 7)) << 3) | (kk & 7));
}

union U32x4 { bf16x8 f; u32 d[4]; uint4 v; };

// ---------------- kernel 0: pack weights/bias, transpose Vtinv, zero proj ----
__global__ __launch_bounds__(256) void k_prep(
    const float* __restrict__ Wii, const float* __restrict__ Wif, const float* __restrict__ Wig,
    const float* __restrict__ Whi, const float* __restrict__ Whit,
    const float* __restrict__ Whf, const float* __restrict__ Whft,
    const float* __restrict__ Whc, const float* __restrict__ Whct,
    const float* __restrict__ Vtinv,
    const float* __restrict__ bi, const float* __restrict__ bfm, const float* __restrict__ bg,
    u16* __restrict__ RW, u16* __restrict__ CW, u16* __restrict__ Vtt,
    u16* __restrict__ biasP, float* __restrict__ proj) {
  const int tid = threadIdx.x, bx = blockIdx.x, y = blockIdx.y;
  if (y < 3) {
    const float* WX  = (y == 0) ? Wii : (y == 1 ? Wif : Wig);
    const float* WHr = (y == 0) ? Whi : (y == 1 ? Whf : Whc);
    const float* WHt = (y == 0) ? Whit : (y == 1 ? Whft : Whct);
    u16* rw = RW + y * Hh * KF;
    u16* cw = CW + y * Hh * KF;
#pragma unroll
    for (int it = 0; it < 4; ++it) {
      int idx = it * 24576 + bx * 256 + tid;   // 0..98303
      int h = idx / KF, t = idx - h * KF;
      float a, c;
      if (t < Ii) { a = WX[h * Ii + t]; c = a; }
      else        { a = WHr[h * Hh + t - Ii]; c = WHt[h * Hh + t - Ii]; }
      rw[idx] = f2bf(a);
      cw[idx] = f2bf(c);
    }
  } else if (y == 3) {
    if (bx < 64) {
      // Vtt[i][k] = Vtinv[k][i], 32x32 LDS tile transpose
      __shared__ u16 tbuf[32][33];
      const int c = tid & 31, r8 = tid >> 5;
      const int tr = bx >> 3, tc = bx & 7;
#pragma unroll
      for (int rr = r8; rr < 32; rr += 8)
        tbuf[rr][c] = f2bf(Vtinv[(tc * 32 + rr) * Hh + tr * 32 + c]);
      __syncthreads();
#pragma unroll
      for (int rr = r8; rr < 32; rr += 8)
        Vtt[(tr * 32 + rr) * Hh + tc * 32 + c] = tbuf[c][rr];
    } else if (bx < 96) {
      // zero proj
      const int base = (bx - 64) * 256 + tid;
      const float4 z = {0.f, 0.f, 0.f, 0.f};
#pragma unroll
      for (int it = 0; it < 4; ++it)
        *(float4*)(proj + (size_t)(it * 8192 + base) * 4) = z;
    }
  } else {
    // biasP: phase-ordered (0=bg,1=bi,2=bf), thread-contiguous in MFMA C order
    const int base = (bx * 256 + tid) * 8;
#pragma unroll
    for (int e8 = 0; e8 < 8; ++e8) {
      int f = base + e8;                    // 0..196607
      int g = f >> 16;
      int r1 = f & 65535;
      int jb = r1 >> 15;
      int r2 = r1 & 32767;
      int kb = r2 >> 13;
      int r3 = r2 & 8191;
      int t  = r3 >> 5;
      int e  = r3 & 31;
      int w = t >> 6, quad = (t >> 4) & 3, r15 = t & 15;
      int ti = e >> 4, tk = (e >> 2) & 3, rr = e & 3;
      int j   = jb * 128 + w * 32 + ti * 16 + quad * 4 + rr;
      int col = kb * 64 + tk * 16 + r15;
      const float* src = (g == 0) ? bg : (g == 1 ? bi : bfm);
      biasP[f] = f2bf(src[j * Hh + col]);
    }
  }
}

// ---------------- gate pass: barrier-free MFMA over K=384 --------------------
// A = RW rows scaled by v_b (register fold), B = CW rows raw from global.
// PHASE 0: p = tanh(zg); PHASE 1: p *= sigm(zi); PHASE 2: c = sigm(zf)*cx + p -> sP
template <int PHASE>
__device__ __forceinline__ void gate_pass(
    const u16* __restrict__ rw, const u16* __restrict__ cw,
    const float* __restrict__ xb, const float* __restrict__ hxb,
    const u16* __restrict__ biasP, const float* __restrict__ cx_b,
    u16* sP, float (&p)[2][4][4],
    int jbase, int k0, int w, int quad, int r15, int jb, int kb, int tid) {
  f32x4 acc[2][4];
#pragma unroll
  for (int ti = 0; ti < 2; ++ti)
#pragma unroll
    for (int tk = 0; tk < 4; ++tk)
#pragma unroll
      for (int r = 0; r < 4; ++r) acc[ti][tk][r] = 0.0f;

#pragma unroll
  for (int kc = 0; kc < 12; ++kc) {
    // v chunk for this quad (8 floats from x or hx, L1-hot)
    const float* vs = (kc < 4) ? (xb + kc * 32) : (hxb + (kc - 4) * 32);
    const float4 v0 = *(const float4*)(vs + quad * 8);
    const float4 v1 = *(const float4*)(vs + quad * 8 + 4);
    // A fragments: raw load + scale + repack (u32 ops only, no u16 arrays)
    bf16x8 fa[2];
#pragma unroll
    for (int ti = 0; ti < 2; ++ti) {
      U32x4 a, o;
      a.v = *(const uint4*)(rw + (jbase + ti * 16 + r15) * KF + kc * 32 + quad * 8);
      o.d[0] = scale2(a.d[0], v0.x, v0.y);
      o.d[1] = scale2(a.d[1], v0.z, v0.w);
      o.d[2] = scale2(a.d[2], v1.x, v1.y);
      o.d[3] = scale2(a.d[3], v1.z, v1.w);
      fa[ti] = o.f;
    }
    // B fragments: raw bf16, zero VALU
    bf16x8 fb[4];
#pragma unroll
    for (int tk = 0; tk < 4; ++tk)
      fb[tk] = *(const bf16x8*)(cw + (k0 + tk * 16 + r15) * KF + kc * 32 + quad * 8);
#pragma unroll
    for (int ti = 0; ti < 2; ++ti)
#pragma unroll
      for (int tk = 0; tk < 4; ++tk)
        acc[ti][tk] = __builtin_amdgcn_mfma_f32_16x16x32_bf16(fa[ti], fb[tk], acc[ti][tk], 0, 0, 0);
  }

  // combine. C/D layout: col(kk)=lane&15, row(j)=quad*4+reg.
  const u16* bp = biasP + (((size_t)(PHASE * 2 + jb) * 4 + kb) * 256 + tid) * 32;
#pragma unroll
  for (int ti = 0; ti < 2; ++ti) {
#pragma unroll
    for (int tk = 0; tk < 4; ++tk) {
      const u32 b01 = *(const u32*)(bp + ti * 16 + tk * 4);
      const u32 b23 = *(const u32*)(bp + ti * 16 + tk * 4 + 2);
      float bias4[4];
      bias4[0] = __uint_as_float(b01 << 16);
      bias4[1] = __uint_as_float(b01 & 0xFFFF0000u);
      bias4[2] = __uint_as_float(b23 << 16);
      bias4[3] = __uint_as_float(b23 & 0xFFFF0000u);
      if (PHASE == 2) {
#pragma unroll
        for (int r = 0; r < 4; ++r) {
          const float cxv = cx_b[(jbase + ti * 16 + quad * 4 + r) * Hh + k0 + tk * 16 + r15];
          const float z = acc[ti][tk][r] + bias4[r];
          const float c = sigm(z) * cxv + p[ti][tk][r];
          const int jl = w * 32 + ti * 16 + quad * 4 + r;   // local j in [0,128)
          const int kk = tk * 16 + r15;
          sP[sp_idx(jl, kk)] = f2bf(c);
        }
      } else {
#pragma unroll
        for (int r = 0; r < 4; ++r) {
          const float z = acc[ti][tk][r] + bias4[r];
          if (PHASE == 0) p[ti][tk][r] = tanh_f(z);
          else            p[ti][tk][r] *= sigm(z);
        }
      }
    }
  }
}

// ---------------- kernel 1: fused gates + cell + down-projection -------------
// grid 4096 = b(512) x jb(2) x kb(4); 256 threads = 4 waves; ONE barrier total.
__global__ __launch_bounds__(256) void k_main(
    const float* __restrict__ x, const float* __restrict__ hx, const float* __restrict__ cx,
    const float* __restrict__ Uinv, const u16* __restrict__ RW, const u16* __restrict__ CW,
    const u16* __restrict__ Vtt, const u16* __restrict__ biasP, float* __restrict__ proj) {
  __shared__ u16 sP[128 * 64];       // 16384 B, swizzled c-tile [j'][kk]

  const int tid  = threadIdx.x;
  const int b    = blockIdx.x >> 3;
  const int jb   = (blockIdx.x >> 2) & 1;
  const int kb   = blockIdx.x & 3;
  const int k0   = kb * KB;
  const int lane = tid & 63;
  const int w    = tid >> 6;
  const int r15  = lane & 15;
  const int quad = lane >> 4;
  const int jbase = jb * 128 + w * 32;   // wave's gate-row slab (global j)

  const float* xb   = x + b * Ii;
  const float* hxb  = hx + b * Hh;
  const float* cx_b = cx + (size_t)b * Hh * Hh;

  float p[2][4][4];
  gate_pass<0>(RW + 2 * Hh * KF, CW + 2 * Hh * KF, xb, hxb, biasP, cx_b, sP, p,
               jbase, k0, w, quad, r15, jb, kb, tid);
  gate_pass<1>(RW + 0 * Hh * KF, CW + 0 * Hh * KF, xb, hxb, biasP, cx_b, sP, p,
               jbase, k0, w, quad, r15, jb, kb, tid);
  gate_pass<2>(RW + 1 * Hh * KF, CW + 1 * Hh * KF, xb, hxb, biasP, cx_b, sP, p,
               jbase, k0, w, quad, r15, jb, kb, tid);

  // ---- projection: M[i,j] = sum_{k in block} Vt_t[i,k] * c[j,k]; then
  //      racc[i] += M[i,j]*Uinv[i,j] over this block's j-range ----
  bf16x8 va[4][2];
#pragma unroll
  for (int ti = 0; ti < 4; ++ti)
#pragma unroll
    for (int ks = 0; ks < 2; ++ks)
      va[ti][ks] = *(const bf16x8*)(Vtt + (w * 64 + ti * 16 + r15) * Hh + k0 + ks * 32 + quad * 8);
  __syncthreads();   // c-tile complete (the ONLY block-wide barrier)

  float racc[4][4];
#pragma unroll
  for (int ti = 0; ti < 4; ++ti)
#pragma unroll
    for (int r = 0; r < 4; ++r) racc[ti][r] = 0.0f;

  for (int jt = 0; jt < 2; ++jt) {
    bf16x8 fbp[2][4];
#pragma unroll
    for (int ks = 0; ks < 2; ++ks)
#pragma unroll
      for (int tj = 0; tj < 4; ++tj) {
        const int j = jt * 64 + tj * 16 + r15;
        const int ch = (ks * 4 + quad) ^ (j & 7);
        fbp[ks][tj] = *(const bf16x8*)(&sP[j * 64 + ch * 8]);
      }
#pragma unroll
    for (int ti = 0; ti < 4; ++ti) {
      f32x4 pacc[4];
#pragma unroll
      for (int tj = 0; tj < 4; ++tj)
#pragma unroll
        for (int r = 0; r < 4; ++r) pacc[tj][r] = 0.0f;
#pragma unroll
      for (int ks = 0; ks < 2; ++ks)
#pragma unroll
        for (int tj = 0; tj < 4; ++tj)
          pacc[tj] = __builtin_amdgcn_mfma_f32_16x16x32_bf16(va[ti][ks], fbp[ks][tj], pacc[tj], 0, 0, 0);
#pragma unroll
      for (int tj = 0; tj < 4; ++tj)
#pragma unroll
        for (int r = 0; r < 4; ++r) {
          const int i  = w * 64 + ti * 16 + quad * 4 + r;
          const int jj = jb * 128 + jt * 64 + tj * 16 + r15;
          racc[ti][r] += pacc[tj][r] * Uinv[i * Hh + jj];
        }
    }
  }

#pragma unroll
  for (int ti = 0; ti < 4; ++ti)
#pragma unroll
    for (int r = 0; r < 4; ++r) {
      float v = racc[ti][r];
      v += __shfl_xor(v, 1);
      v += __shfl_xor(v, 2);
      v += __shfl_xor(v, 4);
      v += __shfl_xor(v, 8);
      if (r15 == 0) atomicAdd(&proj[b * Hh + w * 64 + ti * 16 + quad * 4 + r], v);
    }
}

// ---------------- kernel 2: o-gate + final output ---------------------------
__global__ __launch_bounds__(256) void k_out(
    const float* __restrict__ x, const float* __restrict__ hx,
    const float* __restrict__ Wio, const float* __restrict__ Who,
    const float* __restrict__ bo, const float* __restrict__ proj,
    float* __restrict__ out) {
  __shared__ float sv[KF];
  const int b = blockIdx.x, tid = threadIdx.x;
  const int lane = tid & 63, w = tid >> 6;
  if (tid < Ii) sv[tid] = x[b * Ii + tid];
  sv[Ii + tid] = hx[b * Hh + tid];
  __syncthreads();
  for (int rr = 0; rr < 64; ++rr) {
    const int h = w * 64 + rr;
    float p = Wio[h * Ii + lane]        * sv[lane]
            + Wio[h * Ii + 64 + lane]   * sv[64 + lane]
            + Who[h * Hh + lane]        * sv[128 + lane]
            + Who[h * Hh + 64 + lane]   * sv[192 + lane]
            + Who[h * Hh + 128 + lane]  * sv[256 + lane]
            + Who[h * Hh + 192 + lane]  * sv[320 + lane];
    p += __shfl_xor(p, 32);
    p += __shfl_xor(p, 16);
    p += __shfl_xor(p, 8);
    p += __shfl_xor(p, 4);
    p += __shfl_xor(p, 2);
    p += __shfl_xor(p, 1);
    if (lane == 0)
      out[b * Hh + h] = sigm(p + bo[h]) * sigm(proj[b * Hh + h]);
  }
}

extern "C" void kernel_launch(void* const* d_in, const int* in_sizes, int n_in,
                              void* d_out, int out_size, void* d_ws, size_t ws_size,
                              hipStream_t stream) {
  (void)in_sizes; (void)n_in; (void)out_size; (void)ws_size;
  const float* x    = (const float*)d_in[0];
  const float* hx   = (const float*)d_in[1];
  const float* cx   = (const float*)d_in[2];
  const float* Wii  = (const float*)d_in[3];
  const float* Wif  = (const float*)d_in[4];
  const float* Wig  = (const float*)d_in[5];
  const float* Wio  = (const float*)d_in[6];
  const float* Whi  = (const float*)d_in[7];
  const float* Whit = (const float*)d_in[8];
  const float* Whf  = (const float*)d_in[9];
  const float* Whft = (const float*)d_in[10];
  const float* Whc  = (const float*)d_in[11];
  const float* Whct = (const float*)d_in[12];
  const float* Who  = (const float*)d_in[13];
  const float* Uinv = (const float*)d_in[14];
  const float* Vtinv= (const float*)d_in[15];
  const float* bi   = (const float*)d_in[16];
  const float* bf   = (const float*)d_in[17];
  const float* bg   = (const float*)d_in[18];
  const float* bo   = (const float*)d_in[19];
  float* out = (float*)d_out;

  // workspace (~2.23 MB): RW[3], CW[3], Vtt, biasP (bf16); proj (f32)
  u16* RW    = (u16*)d_ws;
  u16* CW    = RW + 3 * Hh * KF;
  u16* Vtt   = CW + 3 * Hh * KF;
  u16* biasP = Vtt + Hh * Hh;
  float* proj = (float*)(biasP + 3 * Hh * Hh);

  k_prep<<<dim3(96, 5), 256, 0, stream>>>(Wii, Wif, Wig, Whi, Whit, Whf, Whft, Whc, Whct,
                                          Vtinv, bi, bf, bg, RW, CW, Vtt, biasP, proj);
  k_main<<<4096, 256, 0, stream>>>(x, hx, cx, Uinv, RW, CW, Vtt, biasP, proj);
  k_out<<<512, 256, 0, stream>>>(x, hx, Wio, Who, bo, proj, out);
}

// Round 5
// 564.112 us; speedup vs baseline: 1.5397x; 1.4639x over previous
//
#include <hip/hip_runtime.h>
#include <hip/hip_bf16.h>

#define Hh 256
#define Ii 128
#define KF 384    // 128 (x) + 256 (hx) feature dim
#define KB 64     // k-rows per block tile
#define BK 64     // t-chunk per barrier stage
#define LDSB 72   // padded LDS stride (bf16 elems)

typedef __attribute__((ext_vector_type(8))) short bf16x8;
typedef __attribute__((ext_vector_type(4))) float f32x4;
typedef unsigned short u16;
typedef unsigned int u32;

__device__ inline float bf2f(u16 u) { return __uint_as_float(((u32)u) << 16); }
__device__ inline u16 f2bf(float f) {
  u32 u = __float_as_uint(f);
  u += 0x7FFFu + ((u >> 16) & 1u);   // RNE
  return (u16)(u >> 16);
}
__device__ inline u32 pack_bf16x2(float a, float b) {
  __hip_bfloat162 h = __float22bfloat162_rn(make_float2(a, b));
  u32 r; __builtin_memcpy(&r, &h, 4); return r;
}
// scale packed bf16 pair by (va, vb), repack
__device__ inline u32 scale2(u32 packed, float va, float vb) {
  float lo = __uint_as_float(packed << 16) * va;
  float hi = __uint_as_float(packed & 0xFFFF0000u) * vb;
  return pack_bf16x2(lo, hi);
}
__device__ inline float sigm(float x) { return 1.0f / (1.0f + __expf(-x)); }
__device__ inline float tanh_f(float x) { return 1.0f - 2.0f / (1.0f + __expf(2.0f * x)); }

union U32x4 { bf16x8 f; u32 d[4]; uint4 v; };

// ---------------- kernel 0: pack weights/bias/Uinv, transpose Vtinv ----------
__global__ __launch_bounds__(256) void k_prep(
    const float* __restrict__ Wii, const float* __restrict__ Wif, const float* __restrict__ Wig,
    const float* __restrict__ Whi, const float* __restrict__ Whit,
    const float* __restrict__ Whf, const float* __restrict__ Whft,
    const float* __restrict__ Whc, const float* __restrict__ Whct,
    const float* __restrict__ Vtinv, const float* __restrict__ Uinv,
    const float* __restrict__ bi, const float* __restrict__ bfm, const float* __restrict__ bg,
    u16* __restrict__ RW, u16* __restrict__ CW, u16* __restrict__ Vtt,
    u16* __restrict__ biasP, float* __restrict__ UinvP, float* __restrict__ proj) {
  const int tid = threadIdx.x, bx = blockIdx.x, y = blockIdx.y;
  if (y < 3) {
    const float* WX  = (y == 0) ? Wii : (y == 1 ? Wif : Wig);
    const float* WHr = (y == 0) ? Whi : (y == 1 ? Whf : Whc);
    const float* WHt = (y == 0) ? Whit : (y == 1 ? Whft : Whct);
    u16* rw = RW + y * Hh * KF;
    u16* cw = CW + y * Hh * KF;
#pragma unroll
    for (int it = 0; it < 4; ++it) {
      int idx = it * 24576 + bx * 256 + tid;   // 0..98303
      int h = idx / KF, t = idx - h * KF;
      float a, c;
      if (t < Ii) { a = WX[h * Ii + t]; c = a; }
      else        { a = WHr[h * Hh + t - Ii]; c = WHt[h * Hh + t - Ii]; }
      rw[idx] = f2bf(a);
      cw[idx] = f2bf(c);
    }
  } else if (y == 3) {
    if (bx < 64) {
      // Vtt[i][k] = Vtinv[k][i], 32x32 LDS tile transpose
      __shared__ u16 tbuf[32][33];
      const int c = tid & 31, r8 = tid >> 5;
      const int tr = bx >> 3, tc = bx & 7;
#pragma unroll
      for (int rr = r8; rr < 32; rr += 8)
        tbuf[rr][c] = f2bf(Vtinv[(tc * 32 + rr) * Hh + tr * 32 + c]);
      __syncthreads();
#pragma unroll
      for (int rr = r8; rr < 32; rr += 8)
        Vtt[(tr * 32 + rr) * Hh + tc * 32 + c] = tbuf[c][rr];
    } else if (bx < 96) {
      const int base = (bx - 64) * 256 + tid;
      const float4 z = {0.f, 0.f, 0.f, 0.f};
#pragma unroll
      for (int it = 0; it < 4; ++it)
        *(float4*)(proj + (size_t)(it * 8192 + base) * 4) = z;
    }
  } else if (y == 4) {
    // biasP: f = ((ph*4+jb)*4+kb)*4096 + t*16 + e ; e = tk*4+r
    const int base = (bx * 256 + tid) * 8;
#pragma unroll
    for (int e8 = 0; e8 < 8; ++e8) {
      int f = base + e8;                    // 0..196607
      int ph = f >> 16;
      int r1 = f & 65535;
      int jb = r1 >> 14;
      int r2 = r1 & 16383;
      int kb = r2 >> 12;
      int r3 = r2 & 4095;
      int t  = r3 >> 4;
      int e  = r3 & 15;
      int w = t >> 6, quad = (t >> 4) & 3, r15 = t & 15;
      int tk = e >> 2, rr = e & 3;
      int j   = jb * 64 + w * 16 + quad * 4 + rr;
      int col = kb * 64 + tk * 16 + r15;
      const float* src = (ph == 0) ? bg : (ph == 1 ? bi : bfm);
      biasP[f] = f2bf(src[j * Hh + col]);
    }
  } else {
    // UinvP: f = (jb*256 + t)*64 + ti*16 + tj*4 + r
    if (bx < 32) {
      const int base = (bx * 256 + tid) * 8;
#pragma unroll
      for (int e8 = 0; e8 < 8; ++e8) {
        int f = base + e8;                  // 0..65535
        int jb = f >> 14;
        int r2 = f & 16383;
        int t  = r2 >> 6;
        int e  = r2 & 63;
        int ti = e >> 4, tj = (e >> 2) & 3, rr = e & 3;
        int w = t >> 6, quad = (t >> 4) & 3, r15 = t & 15;
        int i = w * 64 + ti * 16 + quad * 4 + rr;
        int j = jb * 64 + tj * 16 + r15;
        UinvP[f] = Uinv[i * Hh + j];
      }
    }
  }
}

// ---------------- kernel 1: fused gates + cell + down-projection -------------
// grid 8192 = b(512) x jb(4) x kb(4); 256 threads = 4 waves.
// Gate tile: 64(j) x 64(k), K=384 in 6 chunks of 64; wave owns 16 j-rows.
// B (CW rows, scaled by v) in LDS dbuf; A (RW rows) raw from global, prefetched.
// p and c in registers; c -> sP once; then projection MFMA + UinvP weighting.
__global__ __launch_bounds__(256) void k_main(
    const float* __restrict__ x, const float* __restrict__ hx, const float* __restrict__ cx,
    const u16* __restrict__ RW, const u16* __restrict__ CW,
    const u16* __restrict__ Vtt, const u16* __restrict__ biasP,
    const float* __restrict__ UinvP, float* __restrict__ proj) {
  __shared__ u16 sB[2 * KB * LDSB];   // 18432 B dbuf scaled-B
  __shared__ u16 sP[KB * LDSB];       //  9216 B c-tile
  __shared__ float sV[KF];            //  1536 B

  const int tid  = threadIdx.x;
  const int b    = blockIdx.x >> 4;
  const int jb   = (blockIdx.x >> 2) & 3;
  const int kb   = blockIdx.x & 3;
  const int k0   = kb * KB;
  const int lane = tid & 63;
  const int w    = tid >> 6;
  const int r15  = lane & 15;
  const int quad = lane >> 4;
  const int jbase = jb * 64 + w * 16;     // wave's 16 gate rows start (global j)
  const int brow = tid >> 2, bcg = tid & 3;

  if (tid < Ii) sV[tid] = x[b * Ii + tid];
  sV[Ii + tid] = hx[b * Hh + tid];

  // phase order: g (tanh), i, f  -> gate indices 2, 0, 1
  const u16* rwp[3] = {RW + 2 * Hh * KF, RW, RW + 1 * Hh * KF};
  const u16* cwp[3] = {CW + 2 * Hh * KF, CW, CW + 1 * Hh * KF};
  const float* cx_b = cx + (size_t)b * Hh * Hh;

  __syncthreads();   // sV ready

  // prologue: raw chunk 0 (phase 0, t0=0) + A frags for chunk 0
  U32x4 n0, n1;
  {
    const u16* src = cwp[0] + (size_t)(k0 + brow) * KF + bcg * 16;
    n0.v = *(const uint4*)src;
    n1.v = *(const uint4*)(src + 8);
  }
  bf16x8 fa[2];
  fa[0] = *(const bf16x8*)(rwp[0] + (size_t)(jbase + r15) * KF + quad * 8);
  fa[1] = *(const bf16x8*)(rwp[0] + (size_t)(jbase + r15) * KF + 32 + quad * 8);
  {
    U32x4 o0, o1;
    const float4 v0 = *(const float4*)(&sV[bcg * 16]);
    const float4 v1 = *(const float4*)(&sV[bcg * 16 + 4]);
    const float4 v2 = *(const float4*)(&sV[bcg * 16 + 8]);
    const float4 v3 = *(const float4*)(&sV[bcg * 16 + 12]);
    o0.d[0] = scale2(n0.d[0], v0.x, v0.y); o0.d[1] = scale2(n0.d[1], v0.z, v0.w);
    o0.d[2] = scale2(n0.d[2], v1.x, v1.y); o0.d[3] = scale2(n0.d[3], v1.z, v1.w);
    o1.d[0] = scale2(n1.d[0], v2.x, v2.y); o1.d[1] = scale2(n1.d[1], v2.z, v2.w);
    o1.d[2] = scale2(n1.d[2], v3.x, v3.y); o1.d[3] = scale2(n1.d[3], v3.z, v3.w);
    u16* dst = sB + brow * LDSB + bcg * 16;
    *(uint4*)dst = o0.v;
    *(uint4*)(dst + 8) = o1.v;
  }
  __syncthreads();   // sB[0] ready

  float p[4][4];

#pragma unroll
  for (int ph = 0; ph < 3; ++ph) {
    f32x4 acc[4];
#pragma unroll
    for (int tk = 0; tk < 4; ++tk)
#pragma unroll
      for (int r = 0; r < 4; ++r) acc[tk][r] = 0.0f;

#pragma unroll
    for (int kc = 0; kc < 6; ++kc) {
      const int sc = ph * 6 + kc;
      const int cur = sc & 1;
      const int nph = (kc < 5) ? ph : (ph < 2 ? ph + 1 : 0);
      const int nt0 = (kc < 5) ? (kc + 1) * BK : 0;
      U32x4 m0, m1;
      bf16x8 fan[2];
      if (sc < 17) {
        const u16* src = cwp[nph] + (size_t)(k0 + brow) * KF + nt0 + bcg * 16;
        m0.v = *(const uint4*)src;
        m1.v = *(const uint4*)(src + 8);
        fan[0] = *(const bf16x8*)(rwp[nph] + (size_t)(jbase + r15) * KF + nt0 + quad * 8);
        fan[1] = *(const bf16x8*)(rwp[nph] + (size_t)(jbase + r15) * KF + nt0 + 32 + quad * 8);
      }
#pragma unroll
      for (int ks = 0; ks < 2; ++ks) {
        bf16x8 fb[4];
#pragma unroll
        for (int tk = 0; tk < 4; ++tk)
          fb[tk] = *(const bf16x8*)(&sB[cur * (KB * LDSB) + (tk * 16 + r15) * LDSB + ks * 32 + quad * 8]);
#pragma unroll
        for (int tk = 0; tk < 4; ++tk)
          acc[tk] = __builtin_amdgcn_mfma_f32_16x16x32_bf16(fa[ks], fb[tk], acc[tk], 0, 0, 0);
      }
      if (sc < 17) {
        U32x4 o0, o1;
        const float4 v0 = *(const float4*)(&sV[nt0 + bcg * 16]);
        const float4 v1 = *(const float4*)(&sV[nt0 + bcg * 16 + 4]);
        const float4 v2 = *(const float4*)(&sV[nt0 + bcg * 16 + 8]);
        const float4 v3 = *(const float4*)(&sV[nt0 + bcg * 16 + 12]);
        o0.d[0] = scale2(m0.d[0], v0.x, v0.y); o0.d[1] = scale2(m0.d[1], v0.z, v0.w);
        o0.d[2] = scale2(m0.d[2], v1.x, v1.y); o0.d[3] = scale2(m0.d[3], v1.z, v1.w);
        o1.d[0] = scale2(m1.d[0], v2.x, v2.y); o1.d[1] = scale2(m1.d[1], v2.z, v2.w);
        o1.d[2] = scale2(m1.d[2], v3.x, v3.y); o1.d[3] = scale2(m1.d[3], v3.z, v3.w);
        u16* dst = sB + (cur ^ 1) * (KB * LDSB) + brow * LDSB + bcg * 16;
        *(uint4*)dst = o0.v;
        *(uint4*)(dst + 8) = o1.v;
        fa[0] = fan[0];
        fa[1] = fan[1];
      }
      if (kc == 5) {
        // combine. C layout: col(k) = tk*16+r15, row(j) = jbase + quad*4 + r
        const u16* bp = biasP + ((size_t)((ph * 4 + jb) * 4 + kb) * 256 + tid) * 16;
        const uint4 b0 = *(const uint4*)bp;
        const uint4 b1 = *(const uint4*)(bp + 8);
        const u32 bw[8] = {b0.x, b0.y, b0.z, b0.w, b1.x, b1.y, b1.z, b1.w};
        if (ph == 2) {
          float cxv[16];
#pragma unroll
          for (int tk = 0; tk < 4; ++tk)
#pragma unroll
            for (int r = 0; r < 4; ++r)
              cxv[tk * 4 + r] = cx_b[(size_t)(jbase + quad * 4 + r) * Hh + k0 + tk * 16 + r15];
#pragma unroll
          for (int tk = 0; tk < 4; ++tk)
#pragma unroll
            for (int r = 0; r < 4; ++r) {
              const int e = tk * 4 + r;
              const float bias = (e & 1) ? __uint_as_float(bw[e >> 1] & 0xFFFF0000u)
                                         : __uint_as_float(bw[e >> 1] << 16);
              const float z = acc[tk][r] + bias;
              const float c = sigm(z) * cxv[e] + p[tk][r];
              sP[(w * 16 + quad * 4 + r) * LDSB + tk * 16 + r15] = f2bf(c);
            }
        } else {
#pragma unroll
          for (int tk = 0; tk < 4; ++tk)
#pragma unroll
            for (int r = 0; r < 4; ++r) {
              const int e = tk * 4 + r;
              const float bias = (e & 1) ? __uint_as_float(bw[e >> 1] & 0xFFFF0000u)
                                         : __uint_as_float(bw[e >> 1] << 16);
              const float z = acc[tk][r] + bias;
              if (ph == 0) p[tk][r] = tanh_f(z);
              else         p[tk][r] *= sigm(z);
            }
        }
      }
      __syncthreads();
    }
  }

  // ---- projection: M[i,j] = sum_k Vt_t[i,k] c[j,k] over this block's 64 k,
  //      64 j; racc[i] += M[i,j]*Uinv[i,j]; wave handles i-slab of 64 ----
  bf16x8 fbp[2][4];
#pragma unroll
  for (int ks = 0; ks < 2; ++ks)
#pragma unroll
    for (int tj = 0; tj < 4; ++tj)
      fbp[ks][tj] = *(const bf16x8*)(&sP[(tj * 16 + r15) * LDSB + ks * 32 + quad * 8]);

  float racc[4][4];
#pragma unroll
  for (int ti = 0; ti < 4; ++ti)
#pragma unroll
    for (int r = 0; r < 4; ++r) racc[ti][r] = 0.0f;

  const float* up = UinvP + ((size_t)jb * 256 + tid) * 64;
#pragma unroll
  for (int ti = 0; ti < 4; ++ti) {
    const bf16x8 va0 = *(const bf16x8*)(Vtt + (size_t)(w * 64 + ti * 16 + r15) * Hh + k0 + quad * 8);
    const bf16x8 va1 = *(const bf16x8*)(Vtt + (size_t)(w * 64 + ti * 16 + r15) * Hh + k0 + 32 + quad * 8);
    f32x4 pacc[4];
#pragma unroll
    for (int tj = 0; tj < 4; ++tj)
#pragma unroll
      for (int r = 0; r < 4; ++r) pacc[tj][r] = 0.0f;
#pragma unroll
    for (int tj = 0; tj < 4; ++tj)
      pacc[tj] = __builtin_amdgcn_mfma_f32_16x16x32_bf16(va0, fbp[0][tj], pacc[tj], 0, 0, 0);
#pragma unroll
    for (int tj = 0; tj < 4; ++tj)
      pacc[tj] = __builtin_amdgcn_mfma_f32_16x16x32_bf16(va1, fbp[1][tj], pacc[tj], 0, 0, 0);
    const float4 u0 = *(const float4*)(up + ti * 16);
    const float4 u1 = *(const float4*)(up + ti * 16 + 4);
    const float4 u2 = *(const float4*)(up + ti * 16 + 8);
    const float4 u3 = *(const float4*)(up + ti * 16 + 12);
    const float uu[16] = {u0.x, u0.y, u0.z, u0.w, u1.x, u1.y, u1.z, u1.w,
                          u2.x, u2.y, u2.z, u2.w, u3.x, u3.y, u3.z, u3.w};
#pragma unroll
    for (int tj = 0; tj < 4; ++tj)
#pragma unroll
      for (int r = 0; r < 4; ++r)
        racc[ti][r] += pacc[tj][r] * uu[tj * 4 + r];
  }

#pragma unroll
  for (int ti = 0; ti < 4; ++ti)
#pragma unroll
    for (int r = 0; r < 4; ++r) {
      float v = racc[ti][r];
      v += __shfl_xor(v, 1);
      v += __shfl_xor(v, 2);
      v += __shfl_xor(v, 4);
      v += __shfl_xor(v, 8);
      if (r15 == 0) atomicAdd(&proj[b * Hh + w * 64 + ti * 16 + quad * 4 + r], v);
    }
}

// ---------------- kernel 2: o-gate + final output ---------------------------
__global__ __launch_bounds__(256) void k_out(
    const float* __restrict__ x, const float* __restrict__ hx,
    const float* __restrict__ Wio, const float* __restrict__ Who,
    const float* __restrict__ bo, const float* __restrict__ proj,
    float* __restrict__ out) {
  __shared__ float sv[KF];
  const int b = blockIdx.x, tid = threadIdx.x;
  const int lane = tid & 63, w = tid >> 6;
  if (tid < Ii) sv[tid] = x[b * Ii + tid];
  sv[Ii + tid] = hx[b * Hh + tid];
  __syncthreads();
  for (int rr = 0; rr < 64; ++rr) {
    const int h = w * 64 + rr;
    float p = Wio[h * Ii + lane]        * sv[lane]
            + Wio[h * Ii + 64 + lane]   * sv[64 + lane]
            + Who[h * Hh + lane]        * sv[128 + lane]
            + Who[h * Hh + 64 + lane]   * sv[192 + lane]
            + Who[h * Hh + 128 + lane]  * sv[256 + lane]
            + Who[h * Hh + 192 + lane]  * sv[320 + lane];
    p += __shfl_xor(p, 32);
    p += __shfl_xor(p, 16);
    p += __shfl_xor(p, 8);
    p += __shfl_xor(p, 4);
    p += __shfl_xor(p, 2);
    p += __shfl_xor(p, 1);
    if (lane == 0)
      out[b * Hh + h] = sigm(p + bo[h]) * sigm(proj[b * Hh + h]);
  }
}

extern "C" void kernel_launch(void* const* d_in, const int* in_sizes, int n_in,
                              void* d_out, int out_size, void* d_ws, size_t ws_size,
                              hipStream_t stream) {
  (void)in_sizes; (void)n_in; (void)out_size; (void)ws_size;
  const float* x    = (const float*)d_in[0];
  const float* hx   = (const float*)d_in[1];
  const float* cx   = (const float*)d_in[2];
  const float* Wii  = (const float*)d_in[3];
  const float* Wif  = (const float*)d_in[4];
  const float* Wig  = (const float*)d_in[5];
  const float* Wio  = (const float*)d_in[6];
  const float* Whi  = (const float*)d_in[7];
  const float* Whit = (const float*)d_in[8];
  const float* Whf  = (const float*)d_in[9];
  const float* Whft = (const float*)d_in[10];
  const float* Whc  = (const float*)d_in[11];
  const float* Whct = (const float*)d_in[12];
  const float* Who  = (const float*)d_in[13];
  const float* Uinv = (const float*)d_in[14];
  const float* Vtinv= (const float*)d_in[15];
  const float* bi   = (const float*)d_in[16];
  const float* bf   = (const float*)d_in[17];
  const float* bg   = (const float*)d_in[18];
  const float* bo   = (const float*)d_in[19];
  float* out = (float*)d_out;

  // workspace (~2.5 MB): RW[3], CW[3], Vtt, biasP (bf16); UinvP, proj (f32)
  u16* RW    = (u16*)d_ws;
  u16* CW    = RW + 3 * Hh * KF;
  u16* Vtt   = CW + 3 * Hh * KF;
  u16* biasP = Vtt + Hh * Hh;
  float* UinvP = (float*)(biasP + 3 * Hh * Hh);
  float* proj  = UinvP + Hh * Hh;

  k_prep<<<dim3(96, 6), 256, 0, stream>>>(Wii, Wif, Wig, Whi, Whit, Whf, Whft, Whc, Whct,
                                          Vtinv, Uinv, bi, bf, bg,
                                          RW, CW, Vtt, biasP, UinvP, proj);
  k_main<<<8192, 256, 0, stream>>>(x, hx, cx, RW, CW, Vtt, biasP, UinvP, proj);
  k_out<<<512, 256, 0, stream>>>(x, hx, Wio, Who, bo, proj, out);
}